// Round 11
// baseline (10790.229 us; speedup 1.0000x reference)
//
#include <hip/hip_runtime.h>
#include <cstdint>
#include <cstddef>

#define T_N 1024
#define B_N 64
#define I_N 512
#define H_N 512
#define G3  (3*H_N)
#define NBLK 256   // 8 groups (8 batches) x 32 blocks (16 units)

typedef _Float16 f16;
typedef _Float16 f16x2 __attribute__((ext_vector_type(2)));
typedef unsigned long long ull;

// exchange ring: data generation d lives in slot SLOT(d) with LSB tag TAG1(d).
#define SLOT(d) (((d)+2)&1)
#define TAG1(d) ((((d)+2)>>1)&1)

__device__ __forceinline__ f16x2 mkh2(float a, float b) {
  f16x2 v; v.x = (_Float16)a; v.y = (_Float16)b; return v;
}
__device__ __forceinline__ f16x2 bch2(unsigned int u) {
  return __builtin_bit_cast(f16x2, u);
}
__device__ __forceinline__ float fdot2_(f16x2 a, f16x2 b, float c) {
#if __has_builtin(__builtin_amdgcn_fdot2)
  return __builtin_amdgcn_fdot2(a, b, c, false);
#else
  return fmaf((float)a.x, (float)b.x, fmaf((float)a.y, (float)b.y, c));
#endif
}
__device__ __forceinline__ float sigm_(float x) { return 1.f / (1.f + __expf(-x)); }
__device__ __forceinline__ float tanhf_(float x) {
  float xx = fminf(15.f, fmaxf(-15.f, x));
  float e = __expf(2.f * xx);
  return (e - 1.f) / (e + 1.f);
}

// ---------------------------------------------------------------------------
// GEMM: C[m][n] = sum_k A[m][k]*W[n][k] + bias[n]   (layer-0 input gates)
// ---------------------------------------------------------------------------
__global__ __launch_bounds__(256) void gemm_nt(
    const float* __restrict__ A,
    const float* __restrict__ W,
    const float* __restrict__ bias,
    float* __restrict__ C,
    int M, int N, int K)
{
  __shared__ float As[32][68];
  __shared__ float Ws[32][68];
  const int tid = threadIdx.x;
  const int n0 = blockIdx.x * 64;
  const int m0 = blockIdx.y * 64;
  const int ty = tid >> 4;
  const int tx = tid & 15;

  float acc[4][4];
#pragma unroll
  for (int i = 0; i < 4; ++i)
#pragma unroll
    for (int jj = 0; jj < 4; ++jj) acc[i][jj] = 0.f;

  for (int k0 = 0; k0 < K; k0 += 32) {
#pragma unroll
    for (int i = 0; i < 2; ++i) {
      int idx = tid + i * 256;
      int r   = idx >> 3;
      int c4  = idx & 7;
      float4 va = *(const float4*)(A + (size_t)(m0 + r) * K + k0 + c4 * 4);
      As[c4*4+0][r] = va.x; As[c4*4+1][r] = va.y;
      As[c4*4+2][r] = va.z; As[c4*4+3][r] = va.w;
      float4 vw = *(const float4*)(W + (size_t)(n0 + r) * K + k0 + c4 * 4);
      Ws[c4*4+0][r] = vw.x; Ws[c4*4+1][r] = vw.y;
      Ws[c4*4+2][r] = vw.z; Ws[c4*4+3][r] = vw.w;
    }
    __syncthreads();
#pragma unroll
    for (int k = 0; k < 32; ++k) {
      float4 a = *(const float4*)&As[k][ty * 4];
      float4 w = *(const float4*)&Ws[k][tx * 4];
      acc[0][0] += a.x*w.x; acc[0][1] += a.x*w.y; acc[0][2] += a.x*w.z; acc[0][3] += a.x*w.w;
      acc[1][0] += a.y*w.x; acc[1][1] += a.y*w.y; acc[1][2] += a.y*w.z; acc[1][3] += a.y*w.w;
      acc[2][0] += a.z*w.x; acc[2][1] += a.z*w.y; acc[2][2] += a.z*w.z; acc[2][3] += a.z*w.w;
      acc[3][0] += a.w*w.x; acc[3][1] += a.w*w.y; acc[3][2] += a.w*w.z; acc[3][3] += a.w*w.w;
    }
    __syncthreads();
  }

  float4 bv = *(const float4*)(bias + n0 + tx * 4);
#pragma unroll
  for (int i = 0; i < 4; ++i) {
    int row = m0 + ty * 4 + i;
    float4 o;
    o.x = acc[i][0] + bv.x; o.y = acc[i][1] + bv.y;
    o.z = acc[i][2] + bv.z; o.w = acc[i][3] + bv.w;
    *(float4*)(C + (size_t)row * N + n0 + tx * 4) = o;
  }
}

// init: pack fp32 hx -> f16 exchange slot SLOT(-1)=1 with tag TAG1(-1)=0
__global__ __launch_bounds__(256) void pack_h_init(
    const float* __restrict__ hx, f16* __restrict__ h0x, f16* __restrict__ h1x)
{
  int i = blockIdx.x * 256 + threadIdx.x;   // 0..32767
  unsigned short a = __builtin_bit_cast(unsigned short, (f16)hx[i]) & 0xFFFEu;
  unsigned short b = __builtin_bit_cast(unsigned short, (f16)hx[B_N * H_N + i]) & 0xFFFEu;
  ((unsigned short*)h0x)[B_N * H_N + i] = a;
  ((unsigned short*)h1x)[B_N * H_N + i] = b;
}

// ---------------------------------------------------------------------------
// conv_w: pre-convert the 3 weight matrices to f16 in the EXACT per-(j,tid)
// layout the scan consumes: wbuf[((j*256+tid)*36 + idx)], idx=(mat*3+q)*4+c.
// ---------------------------------------------------------------------------
__global__ __launch_bounds__(256) void conv_w(
    const float* __restrict__ whh0, const float* __restrict__ wih1,
    const float* __restrict__ whh1, uint4* __restrict__ wbuf)
{
  int gid = blockIdx.x * 256 + threadIdx.x;        // 0..294911
  int idx = gid % 36, rem = gid / 36;
  int tid = rem % 256, j = rem / 256;
  int u = tid >> 4, s = tid & 15;
  int mat = idx / 12, q = (idx % 12) / 4, c = idx % 4;
  const float* src = mat == 0 ? whh0 : (mat == 1 ? wih1 : whh1);
  const float* p = src + (size_t)(q * H_N + 16 * j + u) * H_N + 8 * s + 128 * c;
  uint4 o;
  o.x = __builtin_bit_cast(unsigned int, mkh2(p[0], p[1]));
  o.y = __builtin_bit_cast(unsigned int, mkh2(p[2], p[3]));
  o.z = __builtin_bit_cast(unsigned int, mkh2(p[4], p[5]));
  o.w = __builtin_bit_cast(unsigned int, mkh2(p[6], p[7]));
  wbuf[gid] = o;
}

// dot of 4 f16x2 weight pairs (one uint4) against 4 f16x2 h pairs (one uint4)
#define D4Q(acc, wv, vv)                               \
  acc = fdot2_(bch2((wv).x), bch2((vv).x), acc);       \
  acc = fdot2_(bch2((wv).y), bch2((vv).y), acc);       \
  acc = fdot2_(bch2((wv).z), bch2((vv).z), acc);       \
  acc = fdot2_(bch2((wv).w), bch2((vv).w), acc);

// reduce-scatter 8 accumulators over the 16-lane s-group.
// After: every lane holds the full 16-lane sum for bb = 4(s&1)+2((s>>1)&1)+((s>>2)&1).
template <int NQ>
__device__ __forceinline__ void rscat8(float a[][8], float* r, int s) {
#pragma unroll
  for (int q = 0; q < NQ; ++q) {
    float k4[4];
#pragma unroll
    for (int i = 0; i < 4; ++i) {
      float snd = (s & 1) ? a[q][i] : a[q][4 + i];
      float kp  = (s & 1) ? a[q][4 + i] : a[q][i];
      k4[i] = kp + __shfl_xor(snd, 1);
    }
    float k2[2];
#pragma unroll
    for (int i = 0; i < 2; ++i) {
      float snd = (s & 2) ? k4[i] : k4[2 + i];
      float kp  = (s & 2) ? k4[2 + i] : k4[i];
      k2[i] = kp + __shfl_xor(snd, 2);
    }
    float snd = (s & 4) ? k2[0] : k2[1];
    float kp  = (s & 4) ? k2[1] : k2[0];
    float k1 = kp + __shfl_xor(snd, 4);
    r[q] = k1 + __shfl_xor(k1, 8);
  }
}

// ---------------------------------------------------------------------------
// Fused 2-layer persistent scan. Weight placement (the round-10 lesson: the
// RA spills >136 VGPRs to HBM scratch): A's 12 uint4 stay in registers
// (pinned, fits), B's 24 uint4 live in LDS as manually-managed thread-private
// scratch -- wl[i*256+tid], per-lane 16B stride, conflict-free ds_read_b128,
// re-read per c-iteration (#pragma unroll 1 blocks hoisting) in B's
// poll-shadow phase where LDS latency is free.
// ---------------------------------------------------------------------------
__global__ __launch_bounds__(256, 1) void gru_fused(
    const float* __restrict__ gx,    // [T][64][1536] layer-0 input gates
    const float* __restrict__ hx,    // [2][64][512] fp32 initial h
    const uint4* __restrict__ wbuf,  // pre-converted f16 weights
    const float* __restrict__ bih1, const float* __restrict__ bhh0,
    const float* __restrict__ bhh1,
    float* __restrict__ out,         // [T][64][512]
    float* __restrict__ hT,          // [2][64][512]
    f16* __restrict__ h0x, f16* __restrict__ h1x)  // tagged rings
{
  __shared__ __align__(16) uint4 wl[24 * 256];  // 96 KB B-phase weights
  __shared__ __align__(16) ull sh0q[2][1024];   // 2x8 KB h0 double buffer
  __shared__ __align__(16) ull sh1q[1024];      // 8 KB h1_{t-3}
  __shared__ __align__(8) unsigned short pkA[128], pkB[128];

  const int tid = threadIdx.x;
  const int bid = blockIdx.x;
  const int g = bid & 7;        // batch group (8 batches)
  const int j = bid >> 3;       // block in group -> units 16j..16j+15
  const int u = tid >> 4;       // unit 0..15
  const int s = tid & 15;       // k-split 0..15
  const ull M = 0x0001000100010001ULL;

  // ---- weights: A's 12 uint4 -> pinned registers; B's 24 -> LDS ----
  uint4 wq[12];
  {
    const uint4* wp = wbuf + ((size_t)j * 256 + tid) * 36;
#pragma unroll
    for (int i = 0; i < 12; ++i) wq[i] = wp[i];
#pragma unroll
    for (int i = 0; i < 12; ++i)
      asm volatile("" : "+v"(wq[i].x), "+v"(wq[i].y), "+v"(wq[i].z), "+v"(wq[i].w));
#pragma unroll
    for (int i = 0; i < 24; ++i) wl[i * 256 + tid] = wp[12 + i];
  }

  // gate identity (all 256 lanes; s and s^8 are redundant twins)
  const int bb   = 4 * (s & 1) + 2 * ((s >> 1) & 1) + ((s >> 2) & 1);
  const int unit = 16 * j + u;
  const int gbi  = 8 * g + bb;
  const float bR0 = bhh0[unit], bZ0 = bhh0[H_N + unit], bN0 = bhh0[2 * H_N + unit];
  const float bR1 = bih1[unit] + bhh1[unit];
  const float bZ1 = bih1[H_N + unit] + bhh1[H_N + unit];
  const float bN1x = bih1[2 * H_N + unit], bN1h = bhh1[2 * H_N + unit];
  float hv0 = hx[(size_t)gbi * H_N + unit];
  float hv1 = hx[(size_t)(B_N + gbi) * H_N + unit];

  for (int t = 0; t <= T_N + 1; ++t) {
    const bool runA = (t < T_N);        // compute h0_t
    const bool pollH0 = (t <= T_N);     // stage h0_{t-1}
    const bool runB = (t >= 2);         // compute h1_{t-2}
    const int cur = t & 1;

    // ---- 1. FIRE both rings' tagged loads ----
    const ull* s0 = (const ull*)h0x + (size_t)SLOT(t - 1) * 8192 + (size_t)(8 * g) * 128;
    const ull* s1 = (const ull*)h1x + (size_t)SLOT(t - 3) * 8192 + (size_t)(8 * g) * 128;
    const ull e0 = TAG1(t - 1) ? M : 0ULL;
    const ull e1 = TAG1(t - 3) ? M : 0ULL;
    ull v0[4], v1[4];
    bool k0[4] = {false, false, false, false};
    if (pollH0) {
#pragma unroll
      for (int e = 0; e < 4; ++e)
        v0[e] = __hip_atomic_load(s0 + e * 256 + tid, __ATOMIC_RELAXED, __HIP_MEMORY_SCOPE_AGENT);
    }
    if (runB) {
#pragma unroll
      for (int e = 0; e < 4; ++e)
        v1[e] = __hip_atomic_load(s1 + e * 256 + tid, __ATOMIC_RELAXED, __HIP_MEMORY_SCOPE_AGENT);
    }

    // gx prefetch (plain cached; latency hides under everything below)
    float ir0 = 0, iz0 = 0, in0 = 0;
    if (runA) {
      const float* p = gx + ((size_t)t * B_N + gbi) * G3 + unit;
      ir0 = p[0]; iz0 = p[H_N]; in0 = p[2 * H_N];
    }

    // ---- 2. h1_{t-3} check/poll (expected near-instant) + stage ----
    if (runB) {
      bool k1[4] = {false, false, false, false};
      for (;;) {
        bool all = true;
#pragma unroll
        for (int e = 0; e < 4; ++e) {
          if (!k1[e]) k1[e] = ((v1[e] & M) == e1);
          all = all && k1[e];
        }
        if (__all(all)) break;
        __builtin_amdgcn_s_sleep(1);
#pragma unroll
        for (int e = 0; e < 4; ++e)
          if (!k1[e]) v1[e] = __hip_atomic_load(s1 + e * 256 + tid, __ATOMIC_RELAXED, __HIP_MEMORY_SCOPE_AGENT);
      }
#pragma unroll
      for (int e = 0; e < 4; ++e) sh1q[e * 256 + tid] = v1[e];
    }
    __syncthreads();   // sh1 ready (sh0prev ready since last iter)

    // ---- 3. phase B in the poll shadow: h1_{t-2} ----
    if (runB) {
      float aB[4][8];
#pragma unroll
      for (int q = 0; q < 4; ++q)
#pragma unroll
        for (int b8 = 0; b8 < 8; ++b8) aB[q][b8] = 0.f;
      const uint4* xp = (const uint4*)sh0q[cur ^ 1];   // h0_{t-2}
      const uint4* hp = (const uint4*)sh1q;            // h1_{t-3}
#pragma unroll 1
      for (int c = 0; c < 4; ++c) {
        // 6 weight reads per c from LDS (cannot be hoisted: unroll 1)
        uint4 wx0 = wl[(0 * 4 + c) * 256 + tid];
        uint4 wx1 = wl[(1 * 4 + c) * 256 + tid];
        uint4 wx2 = wl[(2 * 4 + c) * 256 + tid];
        uint4 wh0 = wl[(12 + 0 * 4 + c) * 256 + tid];
        uint4 wh1 = wl[(12 + 1 * 4 + c) * 256 + tid];
        uint4 wh2 = wl[(12 + 2 * 4 + c) * 256 + tid];
#pragma unroll
        for (int b8 = 0; b8 < 8; ++b8) {
          uint4 x = xp[b8 * 64 + s + 16 * c];
          uint4 h = hp[b8 * 64 + s + 16 * c];
          D4Q(aB[0][b8], wx0, x); D4Q(aB[0][b8], wh0, h);
          D4Q(aB[1][b8], wx1, x); D4Q(aB[1][b8], wh1, h);
          D4Q(aB[2][b8], wx2, x);
          D4Q(aB[3][b8], wh2, h);
        }
      }
      float rB[4];
      rscat8<4>(aB, rB, s);
      float r = sigm_(rB[0] + bR1);
      float z = sigm_(rB[1] + bZ1);
      float n = tanhf_(rB[2] + bN1x + r * (rB[3] + bN1h));
      float hy = n + z * (hv1 - n); hv1 = hy;
      if (s < 8) pkB[bb * 16 + u] = __builtin_bit_cast(unsigned short, (f16)hy);
    }

    // ---- 4. check/poll h0_{t-1}, stage into sh0q[cur] ----
    if (pollH0) {
      for (;;) {
        bool all = true;
#pragma unroll
        for (int e = 0; e < 4; ++e) {
          if (!k0[e]) k0[e] = ((v0[e] & M) == e0);
          all = all && k0[e];
        }
        if (__all(all)) break;
        __builtin_amdgcn_s_sleep(1);
#pragma unroll
        for (int e = 0; e < 4; ++e)
          if (!k0[e]) v0[e] = __hip_atomic_load(s0 + e * 256 + tid, __ATOMIC_RELAXED, __HIP_MEMORY_SCOPE_AGENT);
      }
#pragma unroll
      for (int e = 0; e < 4; ++e) sh0q[cur][e * 256 + tid] = v0[e];
    }
    __syncthreads();   // sh0cur + pkB ready

    // ---- 5. phase A (latency-critical): h0_t, register weights ----
    if (runA) {
      float aA[3][8];
#pragma unroll
      for (int q = 0; q < 3; ++q)
#pragma unroll
        for (int b8 = 0; b8 < 8; ++b8) aA[q][b8] = 0.f;
      const uint4* xp = (const uint4*)sh0q[cur];       // h0_{t-1}
#pragma unroll
      for (int b8 = 0; b8 < 8; ++b8) {
        uint4 xc[4];
#pragma unroll
        for (int c = 0; c < 4; ++c) xc[c] = xp[b8 * 64 + s + 16 * c];
        float a0 = aA[0][b8], a1 = aA[1][b8], a2 = aA[2][b8];
#pragma unroll
        for (int c = 0; c < 4; ++c) {
          D4Q(a0, wq[0 * 4 + c], xc[c]);
          D4Q(a1, wq[1 * 4 + c], xc[c]);
          D4Q(a2, wq[2 * 4 + c], xc[c]);
        }
        aA[0][b8] = a0; aA[1][b8] = a1; aA[2][b8] = a2;
      }
      float rA[3];
      rscat8<3>(aA, rA, s);
      float r = sigm_(ir0 + rA[0] + bR0);
      float z = sigm_(iz0 + rA[1] + bZ0);
      float n = tanhf_(in0 + r * (rA[2] + bN0));
      float hy = n + z * (hv0 - n); hv0 = hy;
      if (s < 8) {
        pkA[bb * 16 + u] = __builtin_bit_cast(unsigned short, (f16)hy);
        if (t == T_N - 1) hT[(size_t)gbi * H_N + unit] = hy;
      }
    }
    __syncthreads();   // pkA ready

    // ---- 6. stores ----
    if (tid < 32) {
      if (runA) {      // tagged h0_t -> slot SLOT(t)
        ull v = ((const ull*)pkA)[tid];
        v = (v & ~M) | (TAG1(t) ? M : 0ULL);
        ull* dp = (ull*)h0x + (size_t)SLOT(t) * 8192
                + (size_t)(8 * g + (tid >> 2)) * 128 + 4 * j + (tid & 3);
        __hip_atomic_store(dp, v, __ATOMIC_RELAXED, __HIP_MEMORY_SCOPE_AGENT);
      }
    } else if (tid < 64) {
      if (runB) {
        const int l = tid - 32;
        ull v = ((const ull*)pkB)[l];
        // fp32 out row t-2 (clean, untagged values)
        f16x2 p0 = bch2((unsigned int)v), p1 = bch2((unsigned int)(v >> 32));
        float4 o = {(float)p0.x, (float)p0.y, (float)p1.x, (float)p1.y};
        float* op = out + ((size_t)(t - 2) * B_N + 8 * g + (l >> 2)) * H_N + 16 * j + 4 * (l & 3);
        *(float4*)op = o;
        if (t == T_N + 1)
          *(float4*)(hT + (size_t)(B_N + 8 * g + (l >> 2)) * H_N + 16 * j + 4 * (l & 3)) = o;
        if (t <= T_N) {  // tagged h1_{t-2} -> slot SLOT(t-2)
          v = (v & ~M) | (TAG1(t - 2) ? M : 0ULL);
          ull* dp = (ull*)h1x + (size_t)SLOT(t - 2) * 8192
                  + (size_t)(8 * g + (l >> 2)) * 128 + 4 * j + (l & 3);
          __hip_atomic_store(dp, v, __ATOMIC_RELAXED, __HIP_MEMORY_SCOPE_AGENT);
        }
      }
    }
  }
}

// ---------------------------------------------------------------------------
extern "C" void kernel_launch(void* const* d_in, const int* in_sizes, int n_in,
                              void* d_out, int out_size, void* d_ws, size_t ws_size,
                              hipStream_t stream)
{
  const float* x    = (const float*)d_in[0];
  const float* hx   = (const float*)d_in[1];
  const float* wih0 = (const float*)d_in[2];
  const float* whh0 = (const float*)d_in[3];
  const float* bih0 = (const float*)d_in[4];
  const float* bhh0 = (const float*)d_in[5];
  const float* wih1 = (const float*)d_in[6];
  const float* whh1 = (const float*)d_in[7];
  const float* bih1 = (const float*)d_in[8];
  const float* bhh1 = (const float*)d_in[9];
  float* out = (float*)d_out;            // [T*B*H] output, then [L*B*H] hT

  // workspace: gx [T*B*3H] fp32 | h0x 2*[B*H] f16 | h1x 2*[B*H] f16 | wbuf
  float* gxb = (float*)d_ws;
  f16*   h0x = (f16*)(gxb + (size_t)T_N * B_N * G3);
  f16*   h1x = h0x + 2 * B_N * H_N;
  uint4* wbuf = (uint4*)(h1x + 2 * B_N * H_N);   // 32*256*36 uint4 = 4.5 MB

  pack_h_init<<<128, 256, 0, stream>>>(hx, h0x, h1x);
  conv_w<<<(32 * 256 * 36) / 256, 256, 0, stream>>>(whh0, wih1, whh1, wbuf);

  dim3 gg(G3 / 64, (T_N * B_N) / 64);
  gemm_nt<<<gg, 256, 0, stream>>>(x, wih0, bih0, gxb, T_N * B_N, G3, I_N);

  gru_fused<<<NBLK, 256, 0, stream>>>(gxb, hx, wbuf,
                                      bih1, bhh0, bhh1,
                                      out, out + (size_t)T_N * B_N * H_N,
                                      h0x, h1x);
}

// Round 12
// 8596.575 us; speedup vs baseline: 1.2552x; 1.2552x over previous
//
#include <hip/hip_runtime.h>
#include <cstdint>
#include <cstddef>

#define T_N 1024
#define B_N 64
#define I_N 512
#define H_N 512
#define G3  (3*H_N)
#define NBLK 256   // 8 groups (8 batches) x 32 blocks (16 units)

typedef _Float16 f16;
typedef _Float16 f16x2 __attribute__((ext_vector_type(2)));
typedef unsigned long long ull;

// exchange ring: data generation d lives in slot SLOT(d) with LSB tag TAG1(d).
#define SLOT(d) (((d)+2)&1)
#define TAG1(d) ((((d)+2)>>1)&1)

__device__ __forceinline__ f16x2 mkh2(float a, float b) {
  f16x2 v; v.x = (_Float16)a; v.y = (_Float16)b; return v;
}
__device__ __forceinline__ f16x2 bch2(unsigned int u) {
  return __builtin_bit_cast(f16x2, u);
}
__device__ __forceinline__ float fdot2_(f16x2 a, f16x2 b, float c) {
#if __has_builtin(__builtin_amdgcn_fdot2)
  return __builtin_amdgcn_fdot2(a, b, c, false);
#else
  return fmaf((float)a.x, (float)b.x, fmaf((float)a.y, (float)b.y, c));
#endif
}
__device__ __forceinline__ float sigm_(float x) { return 1.f / (1.f + __expf(-x)); }
__device__ __forceinline__ float tanhf_(float x) {
  float xx = fminf(15.f, fmaxf(-15.f, x));
  float e = __expf(2.f * xx);
  return (e - 1.f) / (e + 1.f);
}

// ---------------------------------------------------------------------------
// GEMM: C[m][n] = sum_k A[m][k]*W[n][k] + bias[n]   (layer-0 input gates)
// ---------------------------------------------------------------------------
__global__ __launch_bounds__(256) void gemm_nt(
    const float* __restrict__ A,
    const float* __restrict__ W,
    const float* __restrict__ bias,
    float* __restrict__ C,
    int M, int N, int K)
{
  __shared__ float As[32][68];
  __shared__ float Ws[32][68];
  const int tid = threadIdx.x;
  const int n0 = blockIdx.x * 64;
  const int m0 = blockIdx.y * 64;
  const int ty = tid >> 4;
  const int tx = tid & 15;

  float acc[4][4];
#pragma unroll
  for (int i = 0; i < 4; ++i)
#pragma unroll
    for (int jj = 0; jj < 4; ++jj) acc[i][jj] = 0.f;

  for (int k0 = 0; k0 < K; k0 += 32) {
#pragma unroll
    for (int i = 0; i < 2; ++i) {
      int idx = tid + i * 256;
      int r   = idx >> 3;
      int c4  = idx & 7;
      float4 va = *(const float4*)(A + (size_t)(m0 + r) * K + k0 + c4 * 4);
      As[c4*4+0][r] = va.x; As[c4*4+1][r] = va.y;
      As[c4*4+2][r] = va.z; As[c4*4+3][r] = va.w;
      float4 vw = *(const float4*)(W + (size_t)(n0 + r) * K + k0 + c4 * 4);
      Ws[c4*4+0][r] = vw.x; Ws[c4*4+1][r] = vw.y;
      Ws[c4*4+2][r] = vw.z; Ws[c4*4+3][r] = vw.w;
    }
    __syncthreads();
#pragma unroll
    for (int k = 0; k < 32; ++k) {
      float4 a = *(const float4*)&As[k][ty * 4];
      float4 w = *(const float4*)&Ws[k][tx * 4];
      acc[0][0] += a.x*w.x; acc[0][1] += a.x*w.y; acc[0][2] += a.x*w.z; acc[0][3] += a.x*w.w;
      acc[1][0] += a.y*w.x; acc[1][1] += a.y*w.y; acc[1][2] += a.y*w.z; acc[1][3] += a.y*w.w;
      acc[2][0] += a.z*w.x; acc[2][1] += a.z*w.y; acc[2][2] += a.z*w.z; acc[2][3] += a.z*w.w;
      acc[3][0] += a.w*w.x; acc[3][1] += a.w*w.y; acc[3][2] += a.w*w.z; acc[3][3] += a.w*w.w;
    }
    __syncthreads();
  }

  float4 bv = *(const float4*)(bias + n0 + tx * 4);
#pragma unroll
  for (int i = 0; i < 4; ++i) {
    int row = m0 + ty * 4 + i;
    float4 o;
    o.x = acc[i][0] + bv.x; o.y = acc[i][1] + bv.y;
    o.z = acc[i][2] + bv.z; o.w = acc[i][3] + bv.w;
    *(float4*)(C + (size_t)row * N + n0 + tx * 4) = o;
  }
}

// init: pack fp32 hx -> f16 exchange slot SLOT(-1)=1 with tag TAG1(-1)=0
__global__ __launch_bounds__(256) void pack_h_init(
    const float* __restrict__ hx, f16* __restrict__ h0x, f16* __restrict__ h1x)
{
  int i = blockIdx.x * 256 + threadIdx.x;   // 0..32767
  unsigned short a = __builtin_bit_cast(unsigned short, (f16)hx[i]) & 0xFFFEu;
  unsigned short b = __builtin_bit_cast(unsigned short, (f16)hx[B_N * H_N + i]) & 0xFFFEu;
  ((unsigned short*)h0x)[B_N * H_N + i] = a;
  ((unsigned short*)h1x)[B_N * H_N + i] = b;
}

// ---------------------------------------------------------------------------
// conv_w: pre-convert the 3 weight matrices to f16 in the EXACT per-(j,tid)
// layout the scan consumes: wbuf[((j*256+tid)*36 + idx)], idx=(mat*3+q)*4+c.
// ---------------------------------------------------------------------------
__global__ __launch_bounds__(256) void conv_w(
    const float* __restrict__ whh0, const float* __restrict__ wih1,
    const float* __restrict__ whh1, uint4* __restrict__ wbuf)
{
  int gid = blockIdx.x * 256 + threadIdx.x;        // 0..294911
  int idx = gid % 36, rem = gid / 36;
  int tid = rem % 256, j = rem / 256;
  int u = tid >> 4, s = tid & 15;
  int mat = idx / 12, q = (idx % 12) / 4, c = idx % 4;
  const float* src = mat == 0 ? whh0 : (mat == 1 ? wih1 : whh1);
  const float* p = src + (size_t)(q * H_N + 16 * j + u) * H_N + 8 * s + 128 * c;
  uint4 o;
  o.x = __builtin_bit_cast(unsigned int, mkh2(p[0], p[1]));
  o.y = __builtin_bit_cast(unsigned int, mkh2(p[2], p[3]));
  o.z = __builtin_bit_cast(unsigned int, mkh2(p[4], p[5]));
  o.w = __builtin_bit_cast(unsigned int, mkh2(p[6], p[7]));
  wbuf[gid] = o;
}

// dot of 4 f16x2 weight pairs (one uint4) against 4 f16x2 h pairs (one uint4)
#define D4Q(acc, wv, vv)                               \
  acc = fdot2_(bch2((wv).x), bch2((vv).x), acc);       \
  acc = fdot2_(bch2((wv).y), bch2((vv).y), acc);       \
  acc = fdot2_(bch2((wv).z), bch2((vv).z), acc);       \
  acc = fdot2_(bch2((wv).w), bch2((vv).w), acc);

// reduce-scatter 8 accumulators over the 16-lane s-group.
// After: every lane holds the full 16-lane sum for bb = 4(s&1)+2((s>>1)&1)+((s>>2)&1).
template <int NQ>
__device__ __forceinline__ void rscat8(float a[][8], float* r, int s) {
#pragma unroll
  for (int q = 0; q < NQ; ++q) {
    float k4[4];
#pragma unroll
    for (int i = 0; i < 4; ++i) {
      float snd = (s & 1) ? a[q][i] : a[q][4 + i];
      float kp  = (s & 1) ? a[q][4 + i] : a[q][i];
      k4[i] = kp + __shfl_xor(snd, 1);
    }
    float k2[2];
#pragma unroll
    for (int i = 0; i < 2; ++i) {
      float snd = (s & 2) ? k4[i] : k4[2 + i];
      float kp  = (s & 2) ? k4[2 + i] : k4[i];
      k2[i] = kp + __shfl_xor(snd, 2);
    }
    float snd = (s & 4) ? k2[0] : k2[1];
    float kp  = (s & 4) ? k2[1] : k2[0];
    float k1 = kp + __shfl_xor(snd, 4);
    r[q] = k1 + __shfl_xor(k1, 8);
  }
}

// ---------------------------------------------------------------------------
// Fused 2-layer persistent scan. Round-12 fix: amdgpu_waves_per_eu(1,1) sets
// the register allocator's occupancy TARGET to 1 wave/EU (launch_bounds only
// sets a minimum), raising its VGPR budget to the full file. All 36 weight
// uint4 (144 VGPRs) are loaded once, asm-pinned, and stay register-resident;
// peak live ~244 < 256 addressable. No in-loop weight memory traffic at all.
// ---------------------------------------------------------------------------
__global__ __attribute__((amdgpu_flat_work_group_size(256, 256),
                          amdgpu_waves_per_eu(1, 1)))
void gru_fused(
    const float* __restrict__ gx,    // [T][64][1536] layer-0 input gates
    const float* __restrict__ hx,    // [2][64][512] fp32 initial h
    const uint4* __restrict__ wbuf,  // pre-converted f16 weights
    const float* __restrict__ bih1, const float* __restrict__ bhh0,
    const float* __restrict__ bhh1,
    float* __restrict__ out,         // [T][64][512]
    float* __restrict__ hT,          // [2][64][512]
    f16* __restrict__ h0x, f16* __restrict__ h1x)  // tagged rings
{
  __shared__ __align__(16) ull sh0q[2][1024];   // 2x8 KB h0 double buffer
  __shared__ __align__(16) ull sh1q[1024];      // 8 KB h1_{t-3}
  __shared__ __align__(8) unsigned short pkA[128], pkB[128];

  const int tid = threadIdx.x;
  const int bid = blockIdx.x;
  const int g = bid & 7;        // batch group (8 batches)
  const int j = bid >> 3;       // block in group -> units 16j..16j+15
  const int u = tid >> 4;       // unit 0..15
  const int s = tid & 15;       // k-split 0..15
  const ull M = 0x0001000100010001ULL;

  // ---- ALL 36 weight uint4 -> registers, loaded once, asm-pinned ----
  uint4 wq[36];
  {
    const uint4* wp = wbuf + ((size_t)j * 256 + tid) * 36;
#pragma unroll
    for (int i = 0; i < 36; ++i) wq[i] = wp[i];
#pragma unroll
    for (int i = 0; i < 36; ++i)
      asm volatile("" : "+v"(wq[i].x), "+v"(wq[i].y), "+v"(wq[i].z), "+v"(wq[i].w));
  }

  // gate identity (all 256 lanes; s and s^8 are redundant twins)
  const int bb   = 4 * (s & 1) + 2 * ((s >> 1) & 1) + ((s >> 2) & 1);
  const int unit = 16 * j + u;
  const int gbi  = 8 * g + bb;
  const float bR0 = bhh0[unit], bZ0 = bhh0[H_N + unit], bN0 = bhh0[2 * H_N + unit];
  const float bR1 = bih1[unit] + bhh1[unit];
  const float bZ1 = bih1[H_N + unit] + bhh1[H_N + unit];
  const float bN1x = bih1[2 * H_N + unit], bN1h = bhh1[2 * H_N + unit];
  float hv0 = hx[(size_t)gbi * H_N + unit];
  float hv1 = hx[(size_t)(B_N + gbi) * H_N + unit];

  for (int t = 0; t <= T_N + 1; ++t) {
    const bool runA = (t < T_N);        // compute h0_t
    const bool pollH0 = (t <= T_N);     // stage h0_{t-1}
    const bool runB = (t >= 2);         // compute h1_{t-2}
    const int cur = t & 1;

    // ---- 1. FIRE both rings' tagged loads ----
    const ull* s0 = (const ull*)h0x + (size_t)SLOT(t - 1) * 8192 + (size_t)(8 * g) * 128;
    const ull* s1 = (const ull*)h1x + (size_t)SLOT(t - 3) * 8192 + (size_t)(8 * g) * 128;
    const ull e0 = TAG1(t - 1) ? M : 0ULL;
    const ull e1 = TAG1(t - 3) ? M : 0ULL;
    ull v0[4], v1[4];
    bool k0[4] = {false, false, false, false};
    if (pollH0) {
#pragma unroll
      for (int e = 0; e < 4; ++e)
        v0[e] = __hip_atomic_load(s0 + e * 256 + tid, __ATOMIC_RELAXED, __HIP_MEMORY_SCOPE_AGENT);
    }
    if (runB) {
#pragma unroll
      for (int e = 0; e < 4; ++e)
        v1[e] = __hip_atomic_load(s1 + e * 256 + tid, __ATOMIC_RELAXED, __HIP_MEMORY_SCOPE_AGENT);
    }

    // gx prefetch (plain cached; latency hides under everything below)
    float ir0 = 0, iz0 = 0, in0 = 0;
    if (runA) {
      const float* p = gx + ((size_t)t * B_N + gbi) * G3 + unit;
      ir0 = p[0]; iz0 = p[H_N]; in0 = p[2 * H_N];
    }

    // ---- 2. h1_{t-3} check/poll (expected near-instant) + stage ----
    if (runB) {
      bool k1[4] = {false, false, false, false};
      for (;;) {
        bool all = true;
#pragma unroll
        for (int e = 0; e < 4; ++e) {
          if (!k1[e]) k1[e] = ((v1[e] & M) == e1);
          all = all && k1[e];
        }
        if (__all(all)) break;
        __builtin_amdgcn_s_sleep(1);
#pragma unroll
        for (int e = 0; e < 4; ++e)
          if (!k1[e]) v1[e] = __hip_atomic_load(s1 + e * 256 + tid, __ATOMIC_RELAXED, __HIP_MEMORY_SCOPE_AGENT);
      }
#pragma unroll
      for (int e = 0; e < 4; ++e) sh1q[e * 256 + tid] = v1[e];
    }
    __syncthreads();   // sh1 ready (sh0prev ready since last iter)

    // ---- 3. phase B in the poll shadow: h1_{t-2} ----
    if (runB) {
      float aB[4][8];
#pragma unroll
      for (int q = 0; q < 4; ++q)
#pragma unroll
        for (int b8 = 0; b8 < 8; ++b8) aB[q][b8] = 0.f;
      const uint4* xp = (const uint4*)sh0q[cur ^ 1];   // h0_{t-2}
      const uint4* hp = (const uint4*)sh1q;            // h1_{t-3}
#pragma unroll
      for (int b8 = 0; b8 < 8; ++b8) {
        uint4 xc[4], hc[4];
#pragma unroll
        for (int c = 0; c < 4; ++c) { xc[c] = xp[b8 * 64 + s + 16 * c]; hc[c] = hp[b8 * 64 + s + 16 * c]; }
        float a0 = aB[0][b8], a1 = aB[1][b8], a2 = aB[2][b8], a3 = aB[3][b8];
#pragma unroll
        for (int c = 0; c < 4; ++c) {
          D4Q(a0, wq[12 + 0 * 4 + c], xc[c]); D4Q(a0, wq[24 + 0 * 4 + c], hc[c]);
          D4Q(a1, wq[12 + 1 * 4 + c], xc[c]); D4Q(a1, wq[24 + 1 * 4 + c], hc[c]);
          D4Q(a2, wq[12 + 2 * 4 + c], xc[c]);
          D4Q(a3, wq[24 + 2 * 4 + c], hc[c]);
        }
        aB[0][b8] = a0; aB[1][b8] = a1; aB[2][b8] = a2; aB[3][b8] = a3;
      }
      float rB[4];
      rscat8<4>(aB, rB, s);
      float r = sigm_(rB[0] + bR1);
      float z = sigm_(rB[1] + bZ1);
      float n = tanhf_(rB[2] + bN1x + r * (rB[3] + bN1h));
      float hy = n + z * (hv1 - n); hv1 = hy;
      if (s < 8) pkB[bb * 16 + u] = __builtin_bit_cast(unsigned short, (f16)hy);
    }

    // ---- 4. check/poll h0_{t-1}, stage into sh0q[cur] ----
    if (pollH0) {
      for (;;) {
        bool all = true;
#pragma unroll
        for (int e = 0; e < 4; ++e) {
          if (!k0[e]) k0[e] = ((v0[e] & M) == e0);
          all = all && k0[e];
        }
        if (__all(all)) break;
        __builtin_amdgcn_s_sleep(1);
#pragma unroll
        for (int e = 0; e < 4; ++e)
          if (!k0[e]) v0[e] = __hip_atomic_load(s0 + e * 256 + tid, __ATOMIC_RELAXED, __HIP_MEMORY_SCOPE_AGENT);
      }
#pragma unroll
      for (int e = 0; e < 4; ++e) sh0q[cur][e * 256 + tid] = v0[e];
    }
    __syncthreads();   // sh0cur + pkB ready

    // ---- 5. phase A (latency-critical): h0_t, register weights ----
    if (runA) {
      float aA[3][8];
#pragma unroll
      for (int q = 0; q < 3; ++q)
#pragma unroll
        for (int b8 = 0; b8 < 8; ++b8) aA[q][b8] = 0.f;
      const uint4* xp = (const uint4*)sh0q[cur];       // h0_{t-1}
#pragma unroll
      for (int b8 = 0; b8 < 8; ++b8) {
        uint4 xc[4];
#pragma unroll
        for (int c = 0; c < 4; ++c) xc[c] = xp[b8 * 64 + s + 16 * c];
        float a0 = aA[0][b8], a1 = aA[1][b8], a2 = aA[2][b8];
#pragma unroll
        for (int c = 0; c < 4; ++c) {
          D4Q(a0, wq[0 * 4 + c], xc[c]);
          D4Q(a1, wq[1 * 4 + c], xc[c]);
          D4Q(a2, wq[2 * 4 + c], xc[c]);
        }
        aA[0][b8] = a0; aA[1][b8] = a1; aA[2][b8] = a2;
      }
      float rA[3];
      rscat8<3>(aA, rA, s);
      float r = sigm_(ir0 + rA[0] + bR0);
      float z = sigm_(iz0 + rA[1] + bZ0);
      float n = tanhf_(in0 + r * (rA[2] + bN0));
      float hy = n + z * (hv0 - n); hv0 = hy;
      if (s < 8) {
        pkA[bb * 16 + u] = __builtin_bit_cast(unsigned short, (f16)hy);
        if (t == T_N - 1) hT[(size_t)gbi * H_N + unit] = hy;
      }
    }
    __syncthreads();   // pkA ready

    // ---- 6. stores ----
    if (tid < 32) {
      if (runA) {      // tagged h0_t -> slot SLOT(t)
        ull v = ((const ull*)pkA)[tid];
        v = (v & ~M) | (TAG1(t) ? M : 0ULL);
        ull* dp = (ull*)h0x + (size_t)SLOT(t) * 8192
                + (size_t)(8 * g + (tid >> 2)) * 128 + 4 * j + (tid & 3);
        __hip_atomic_store(dp, v, __ATOMIC_RELAXED, __HIP_MEMORY_SCOPE_AGENT);
      }
    } else if (tid < 64) {
      if (runB) {
        const int l = tid - 32;
        ull v = ((const ull*)pkB)[l];
        // fp32 out row t-2 (clean, untagged values)
        f16x2 p0 = bch2((unsigned int)v), p1 = bch2((unsigned int)(v >> 32));
        float4 o = {(float)p0.x, (float)p0.y, (float)p1.x, (float)p1.y};
        float* op = out + ((size_t)(t - 2) * B_N + 8 * g + (l >> 2)) * H_N + 16 * j + 4 * (l & 3);
        *(float4*)op = o;
        if (t == T_N + 1)
          *(float4*)(hT + (size_t)(B_N + 8 * g + (l >> 2)) * H_N + 16 * j + 4 * (l & 3)) = o;
        if (t <= T_N) {  // tagged h1_{t-2} -> slot SLOT(t-2)
          v = (v & ~M) | (TAG1(t - 2) ? M : 0ULL);
          ull* dp = (ull*)h1x + (size_t)SLOT(t - 2) * 8192
                  + (size_t)(8 * g + (l >> 2)) * 128 + 4 * j + (l & 3);
          __hip_atomic_store(dp, v, __ATOMIC_RELAXED, __HIP_MEMORY_SCOPE_AGENT);
        }
      }
    }
  }
}

// ---------------------------------------------------------------------------
extern "C" void kernel_launch(void* const* d_in, const int* in_sizes, int n_in,
                              void* d_out, int out_size, void* d_ws, size_t ws_size,
                              hipStream_t stream)
{
  const float* x    = (const float*)d_in[0];
  const float* hx   = (const float*)d_in[1];
  const float* wih0 = (const float*)d_in[2];
  const float* whh0 = (const float*)d_in[3];
  const float* bih0 = (const float*)d_in[4];
  const float* bhh0 = (const float*)d_in[5];
  const float* wih1 = (const float*)d_in[6];
  const float* whh1 = (const float*)d_in[7];
  const float* bih1 = (const float*)d_in[8];
  const float* bhh1 = (const float*)d_in[9];
  float* out = (float*)d_out;            // [T*B*H] output, then [L*B*H] hT

  // workspace: gx [T*B*3H] fp32 | h0x 2*[B*H] f16 | h1x 2*[B*H] f16 | wbuf
  float* gxb = (float*)d_ws;
  f16*   h0x = (f16*)(gxb + (size_t)T_N * B_N * G3);
  f16*   h1x = h0x + 2 * B_N * H_N;
  uint4* wbuf = (uint4*)(h1x + 2 * B_N * H_N);   // 32*256*36 uint4 = 4.5 MB

  pack_h_init<<<128, 256, 0, stream>>>(hx, h0x, h1x);
  conv_w<<<(32 * 256 * 36) / 256, 256, 0, stream>>>(whh0, wih1, whh1, wbuf);

  dim3 gg(G3 / 64, (T_N * B_N) / 64);
  gemm_nt<<<gg, 256, 0, stream>>>(x, wih0, bih0, gxb, T_N * B_N, G3, I_N);

  gru_fused<<<NBLK, 256, 0, stream>>>(gxb, hx, wbuf,
                                      bih1, bhh0, bhh1,
                                      out, out + (size_t)T_N * B_N * H_N,
                                      h0x, h1x);
}